// Round 8
// baseline (230.301 us; speedup 1.0000x reference)
//
#include <hip/hip_runtime.h>
#include <hip/hip_bf16.h>

#define NNODES 10000
#define NB 8
#define NF 128
#define NE 160000

typedef __attribute__((ext_vector_type(8))) short  short8;   // 8 bf16 (A/B frag)
typedef __attribute__((ext_vector_type(8))) unsigned short ushort8;
typedef __attribute__((ext_vector_type(4))) float  f32x4;    // MFMA acc

// fp32 -> bf16 (RNE) scalar
__device__ __forceinline__ unsigned short f2b(float f) {
    union { float f; unsigned u; } v; v.f = f;
    unsigned r = v.u + 0x7FFF + ((v.u >> 16) & 1);
    return (unsigned short)(r >> 16);
}
// packed pair fp32 -> bf16x2 (v_cvt_pk_bf16_f32)
__device__ __forceinline__ unsigned int f2b2(float a, float b) {
    union { __hip_bfloat162 h; unsigned int u; } v;
    v.h = __float22bfloat162_rn(make_float2(a, b));
    return v.u;
}
__device__ __forceinline__ float b2f_lo(unsigned u) {
    union { unsigned u; float f; } v; v.u = u << 16; return v.f;
}
__device__ __forceinline__ float b2f_hi(unsigned u) {
    union { unsigned u; float f; } v; v.u = u & 0xffff0000u; return v.f;
}

// Swizzled LDS byte offset for a logical [R][128] ushort tile.
__device__ __forceinline__ int swz(int r, int cbyte) {
    return r * 256 + (cbyte ^ ((r & 7) << 4));
}

// ---------------- preprocessing ----------------

__global__ void k_init(int* __restrict__ cnt, int* __restrict__ fill,
                       const float* __restrict__ W1, unsigned short* __restrict__ Wt1,
                       const float* __restrict__ W2, unsigned short* __restrict__ Wt2) {
    const int bid = blockIdx.x;
    const int t = threadIdx.x;
    if (bid < 79) {                       // 79*256 = 20224 >= 2*NNODES
        int i = bid * 256 + t;
        if (i < NNODES) cnt[i] = 0;
        else if (i < 2 * NNODES) fill[i - NNODES] = 0;
    } else {                              // 128 blocks -> 32768 weight elems
        int id = (bid - 79) * 256 + t;
        const float* W = (id < 16384) ? W1 : W2;
        unsigned short* Wt = (id < 16384) ? Wt1 : Wt2;
        int j = id & 16383;
        int n = j >> 7, k = j & 127;
        Wt[(size_t)n * 128 + k] = f2b(W[(size_t)k * 128 + n]);
    }
}

__global__ void k_count(const int* __restrict__ ei, int* __restrict__ cnt) {
    int e = blockIdx.x * blockDim.x + threadIdx.x;
    if (e < NE) atomicAdd(&cnt[ei[NE + e]], 1);
}

// one-block scan of cnt -> row_ptr, plus dinv = rsqrt(deg+1)
__global__ void k_scan(const int* __restrict__ cnt, int* __restrict__ row_ptr,
                       float* __restrict__ dinv) {
    __shared__ int part[1024];
    int t = threadIdx.x;
    const int CH = (NNODES + 1023) / 1024;  // 10
    int lo = t * CH, hi = min(lo + CH, NNODES);
    int s = 0;
    for (int i = lo; i < hi; i++) {
        int c = cnt[i];
        dinv[i] = rsqrtf((float)(c + 1));
        s += c;
    }
    part[t] = s;
    __syncthreads();
    for (int off = 1; off < 1024; off <<= 1) {
        int v = (t >= off) ? part[t - off] : 0;
        __syncthreads();
        part[t] += v;
        __syncthreads();
    }
    int base = part[t] - s;
    for (int i = lo; i < hi; i++) { row_ptr[i] = base; base += cnt[i]; }
    if (t == 1023) row_ptr[NNODES] = part[1023];
}

// CSR scatter; edge[pos] = src(16b) | bf16(w) << 16   (4 B per edge)
__global__ void k_scatter(const int* __restrict__ ei, const int* __restrict__ row_ptr,
                          int* __restrict__ fill, const float* __restrict__ dinv,
                          unsigned int* __restrict__ edge) {
    int e = blockIdx.x * blockDim.x + threadIdx.x;
    if (e >= NE) return;
    int s = ei[e];
    int d = ei[NE + e];
    int pos = row_ptr[d] + atomicAdd(&fill[d], 1);
    edge[pos] = (unsigned)s | ((unsigned)f2b(dinv[s] * dinv[d]) << 16);
}

// ---------------- layer-1 matmul (bf16 MFMA, fp32 input) ----------------
// 128-row tile / 256 threads -> 625 blocks. Measured-best config (222.7 total):
// the 64-row variant re-stages W twice as often and lost 5.6 us (R7 bench).
__global__ __launch_bounds__(256) void k_mm_mfma(const float* __restrict__ Ap,
                                                 const unsigned short* __restrict__ Wt,
                                                 unsigned short* __restrict__ Cn) {
    __shared__ unsigned short wlds[128 * 128];  // 32 KB, XOR-swizzled; reused as C-stage
    const int t = threadIdx.x;
    {   // stage Wt (32 KB), 2 threads/row, 64 ushorts each
        const int r = t >> 1, h = t & 1;
        const ushort8* src = (const ushort8*)(Wt + r * 128 + h * 64);
        #pragma unroll
        for (int i = 0; i < 8; i++)
            *(ushort8*)((char*)wlds + swz(r, h * 128 + i * 16)) = src[i];
    }
    __syncthreads();

    const int wid = t >> 6, lane = t & 63;
    const int quad = lane >> 4, l16 = lane & 15;
    const int m0 = blockIdx.x * 128 + (wid & 1) * 64;  // act row base for this wave
    const int nb = (wid >> 1) * 64;                    // feature base
    const int kq = quad * 8;

    f32x4 acc[4][4] = {};

    #pragma unroll
    for (int ks = 0; ks < 128; ks += 32) {
        short8 bf[4];
        #pragma unroll
        for (int mi = 0; mi < 4; mi++) {
            const float* p = Ap + (size_t)(m0 + mi * 16 + l16) * 128 + ks + kq;
            float4 u0 = *(const float4*)p;
            float4 u1 = *(const float4*)(p + 4);
            union { uint4 u4; short8 s8; } cv;
            cv.u4.x = f2b2(u0.x, u0.y); cv.u4.y = f2b2(u0.z, u0.w);
            cv.u4.z = f2b2(u1.x, u1.y); cv.u4.w = f2b2(u1.z, u1.w);
            bf[mi] = cv.s8;
        }
        short8 af[4];
        #pragma unroll
        for (int ni = 0; ni < 4; ni++) {
            const int row = nb + ni * 16 + l16;
            af[ni] = *(const short8*)((const char*)wlds + swz(row, (ks + kq) * 2));
        }
        #pragma unroll
        for (int mi = 0; mi < 4; mi++)
            #pragma unroll
            for (int ni = 0; ni < 4; ni++)
                acc[mi][ni] = __builtin_amdgcn_mfma_f32_16x16x32_bf16(
                    af[ni], bf[mi], acc[mi][ni], 0, 0, 0);
    }

    // ---- epilogue: stage 128x128 bf16 tile in LDS, coalesced stores ----
    __syncthreads();  // done reading W tile; reuse wlds
    {
        const int rbase = (wid & 1) * 64;
        #pragma unroll
        for (int mi = 0; mi < 4; mi++) {
            int rr = rbase + mi * 16 + l16;
            #pragma unroll
            for (int ni = 0; ni < 4; ni++) {
                uint2 p;
                p.x = f2b2(acc[mi][ni][0], acc[mi][ni][1]);
                p.y = f2b2(acc[mi][ni][2], acc[mi][ni][3]);
                *(uint2*)((char*)wlds + swz(rr, (nb + ni * 16 + quad * 4) * 2)) = p;
            }
        }
    }
    __syncthreads();
    {
        const int r = t >> 1, h = t & 1;     // 128 rows x 2 halves of 128 B
        size_t gm = (size_t)blockIdx.x * 128 + r;   // row index in [B,N] order
        unsigned short* dst = Cn + gm * 128 + h * 64;
        #pragma unroll
        for (int i = 0; i < 8; i++)
            *(ushort8*)(dst + i * 8) =
                *(const ushort8*)((const char*)wlds + swz(r, h * 128 + i * 16));
    }
}

// ---------------- fused layer-1 aggregation + layer-2 matmul ----------------
// 32-row tile / 512 threads -> 2504 blocks; b = blockIdx&7 keeps batch->XCD L2
// binding (R5: losing it = 10x FETCH). Gather is CLEAN paired-edge dwordx2:
// lanes 0-31 own edge e, lanes 32-63 own e+1; lane holds feats [4*l31,4*l31+4)
// (8 B). Halves gather instructions + decode at IDENTICAL line count and zero
// wasted slots (R4's masked 16-step loop gathered ~1.9x slots/row -- that, not
// the pairing, was its regression). Combine: 4x shfl_xor(32) once per row.
__global__ __launch_bounds__(512) void k_fused(const unsigned int* __restrict__ hNu,
                                               const float* __restrict__ bias,
                                               const int* __restrict__ row_ptr,
                                               const unsigned int* __restrict__ edge,
                                               const float* __restrict__ dinv,
                                               const unsigned short* __restrict__ Wt,
                                               unsigned short* __restrict__ Cn) {
    __shared__ unsigned short alds[32 * 128];   // 8 KB act tile; reused as C-stage
    const int t = threadIdx.x;
    const int b = blockIdx.x & 7;
    const int g = blockIdx.x >> 3;
    const int n0 = g * 32;
    const int wid = __builtin_amdgcn_readfirstlane(t >> 6);
    const int lane = t & 63;
    const int l31 = lane & 31;
    const int hi = lane >> 5;                   // which edge of the pair

    const unsigned int* base = hNu + (size_t)b * NNODES * 64 + l31 * 2;  // + n*64
    const float4 bias4 = *(const float4*)(bias + l31 * 4);

    #pragma unroll
    for (int i = 0; i < 4; i++) {
        const int r = wid * 4 + i;       // local row in [0,32)
        const int n = n0 + r;
        float a0 = 0.f, a1 = 0.f, a2 = 0.f, a3 = 0.f;
        if (n < NNODES) {                // wave-uniform guard (tail tile)
            const float di = dinv[n];
            const float ws = hi ? 0.f : di * di;   // upper half 0: no double count
            const uint2 su = *(const uint2*)(base + (size_t)n * 64);
            a0 = b2f_lo(su.x) * ws; a1 = b2f_hi(su.x) * ws;
            a2 = b2f_lo(su.y) * ws; a3 = b2f_hi(su.y) * ws;
            int e = row_ptr[n];
            const int e1 = row_ptr[n + 1];
            for (; e + 8 <= e1; e += 8) {         // 4 pairs = 8 edges
                unsigned int Ew[4];
                #pragma unroll
                for (int k = 0; k < 4; k++) {
                    const unsigned int Ea = edge[e + 2 * k];
                    const unsigned int Eb = edge[e + 2 * k + 1];
                    Ew[k] = hi ? Eb : Ea;
                }
                uint2 U[4];
                #pragma unroll
                for (int k = 0; k < 4; k++)
                    U[k] = *(const uint2*)(base + (size_t)(Ew[k] & 0xffffu) * 64);
                #pragma unroll
                for (int k = 0; k < 4; k++) {
                    const float w = b2f_hi(Ew[k]);
                    a0 = fmaf(b2f_lo(U[k].x), w, a0);
                    a1 = fmaf(b2f_hi(U[k].x), w, a1);
                    a2 = fmaf(b2f_lo(U[k].y), w, a2);
                    a3 = fmaf(b2f_hi(U[k].y), w, a3);
                }
            }
            for (; e + 2 <= e1; e += 2) {         // single pair
                const unsigned int Ea = edge[e];
                const unsigned int Eb = edge[e + 1];
                const unsigned int Ew = hi ? Eb : Ea;
                const uint2 U = *(const uint2*)(base + (size_t)(Ew & 0xffffu) * 64);
                const float w = b2f_hi(Ew);
                a0 = fmaf(b2f_lo(U.x), w, a0);
                a1 = fmaf(b2f_hi(U.x), w, a1);
                a2 = fmaf(b2f_lo(U.y), w, a2);
                a3 = fmaf(b2f_hi(U.y), w, a3);
            }
            if (e < e1) {                          // odd leftover: lower half only
                const unsigned int Ew = edge[e];
                const uint2 U = *(const uint2*)(base + (size_t)(Ew & 0xffffu) * 64);
                const float w = hi ? 0.f : b2f_hi(Ew);
                a0 = fmaf(b2f_lo(U.x), w, a0);
                a1 = fmaf(b2f_hi(U.x), w, a1);
                a2 = fmaf(b2f_lo(U.y), w, a2);
                a3 = fmaf(b2f_hi(U.y), w, a3);
            }
        }
        // combine the two edge-halves
        a0 += __shfl_xor(a0, 32);
        a1 += __shfl_xor(a1, 32);
        a2 += __shfl_xor(a2, 32);
        a3 += __shfl_xor(a3, 32);
        if (lane < 32) {
            uint2 pk;
            pk.x = f2b2(fmaxf(a0 + bias4.x, 0.f), fmaxf(a1 + bias4.y, 0.f));
            pk.y = f2b2(fmaxf(a2 + bias4.z, 0.f), fmaxf(a3 + bias4.w, 0.f));
            *(uint2*)((char*)alds + swz(r, l31 * 8)) = pk;
        }
    }
    __syncthreads();

    // ---- phase B: MFMA, act rows from LDS, W2 frags from global (L2-hot) ----
    const int quad = lane >> 4, l16 = lane & 15;
    const int kq = quad * 8;
    const int rh = (wid & 1) * 16;       // act row half (16 rows)
    const int nb = (wid >> 1) * 32;      // feature quarter (32 feats)

    f32x4 acc[2] = {};
    #pragma unroll
    for (int ks = 0; ks < 128; ks += 32) {
        short8 bf;
        {
            const int row = rh + l16;
            bf = *(const short8*)((const char*)alds + swz(row, (ks + kq) * 2));
        }
        short8 af[2];
        #pragma unroll
        for (int ni = 0; ni < 2; ni++)
            af[ni] = *(const short8*)(Wt + (size_t)(nb + ni * 16 + l16) * 128 + ks + kq);
        #pragma unroll
        for (int ni = 0; ni < 2; ni++)
            acc[ni] = __builtin_amdgcn_mfma_f32_16x16x32_bf16(
                af[ni], bf, acc[ni], 0, 0, 0);
    }

    __syncthreads();  // done reading alds; reuse as C-stage
    {
        const int rr = rh + l16;
        #pragma unroll
        for (int ni = 0; ni < 2; ni++) {
            uint2 p;
            p.x = f2b2(acc[ni][0], acc[ni][1]);
            p.y = f2b2(acc[ni][2], acc[ni][3]);
            *(uint2*)((char*)alds + swz(rr, (nb + ni * 16 + quad * 4) * 2)) = p;
        }
    }
    __syncthreads();
    {
        const int r = t >> 4, h = t & 15;  // 32 rows x 16 chunks of 16 B
        const int n = n0 + r;
        if (n < NNODES) {
            unsigned short* dst = Cn + ((size_t)b * NNODES + n) * 128 + h * 8;
            *(ushort8*)dst = *(const ushort8*)((const char*)alds + swz(r, h * 16));
        }
    }
}

// ---------------- layer-2 aggregation + LayerNorm ----------------
// Same clean paired-edge dwordx2 gather; LN over 32-lane half (4 feats/lane).
__global__ __launch_bounds__(256) void k_agg_ln(const unsigned int* __restrict__ hNu,
                                                const float* __restrict__ bias,
                                                const int* __restrict__ row_ptr,
                                                const unsigned int* __restrict__ edge,
                                                const float* __restrict__ dinv,
                                                const float* __restrict__ ln_w,
                                                const float* __restrict__ ln_b,
                                                float* __restrict__ out) {
    const int t = threadIdx.x;
    const int b = blockIdx.x & 7;
    const int g = blockIdx.x >> 3;
    const int wid = __builtin_amdgcn_readfirstlane(t >> 6);
    const int lane = t & 63;
    const int l31 = lane & 31;
    const int hi = lane >> 5;
    const int n = g * 4 + wid;

    const unsigned int* base = hNu + (size_t)b * NNODES * 64 + l31 * 2;
    const float4 bias4 = *(const float4*)(bias + l31 * 4);

    const float di = dinv[n];
    const float ws = hi ? 0.f : di * di;
    const uint2 su = *(const uint2*)(base + (size_t)n * 64);
    float a0 = b2f_lo(su.x) * ws, a1 = b2f_hi(su.x) * ws;
    float a2 = b2f_lo(su.y) * ws, a3 = b2f_hi(su.y) * ws;

    int e = row_ptr[n];
    const int e1 = row_ptr[n + 1];
    for (; e + 8 <= e1; e += 8) {
        unsigned int Ew[4];
        #pragma unroll
        for (int k = 0; k < 4; k++) {
            const unsigned int Ea = edge[e + 2 * k];
            const unsigned int Eb = edge[e + 2 * k + 1];
            Ew[k] = hi ? Eb : Ea;
        }
        uint2 U[4];
        #pragma unroll
        for (int k = 0; k < 4; k++)
            U[k] = *(const uint2*)(base + (size_t)(Ew[k] & 0xffffu) * 64);
        #pragma unroll
        for (int k = 0; k < 4; k++) {
            const float w = b2f_hi(Ew[k]);
            a0 = fmaf(b2f_lo(U[k].x), w, a0);
            a1 = fmaf(b2f_hi(U[k].x), w, a1);
            a2 = fmaf(b2f_lo(U[k].y), w, a2);
            a3 = fmaf(b2f_hi(U[k].y), w, a3);
        }
    }
    for (; e + 2 <= e1; e += 2) {
        const unsigned int Ea = edge[e];
        const unsigned int Eb = edge[e + 1];
        const unsigned int Ew = hi ? Eb : Ea;
        const uint2 U = *(const uint2*)(base + (size_t)(Ew & 0xffffu) * 64);
        const float w = b2f_hi(Ew);
        a0 = fmaf(b2f_lo(U.x), w, a0);
        a1 = fmaf(b2f_hi(U.x), w, a1);
        a2 = fmaf(b2f_lo(U.y), w, a2);
        a3 = fmaf(b2f_hi(U.y), w, a3);
    }
    if (e < e1) {
        const unsigned int Ew = edge[e];
        const uint2 U = *(const uint2*)(base + (size_t)(Ew & 0xffffu) * 64);
        const float w = hi ? 0.f : b2f_hi(Ew);
        a0 = fmaf(b2f_lo(U.x), w, a0);
        a1 = fmaf(b2f_hi(U.x), w, a1);
        a2 = fmaf(b2f_lo(U.y), w, a2);
        a3 = fmaf(b2f_hi(U.y), w, a3);
    }

    a0 += __shfl_xor(a0, 32);
    a1 += __shfl_xor(a1, 32);
    a2 += __shfl_xor(a2, 32);
    a3 += __shfl_xor(a3, 32);
    a0 += bias4.x; a1 += bias4.y; a2 += bias4.z; a3 += bias4.w;

    // LayerNorm over 128 feats = 4/lane x 32 lanes (reduce within 32-lane half;
    // lanes 0-31 hold the valid combined values)
    float s1 = a0 + a1 + a2 + a3;
    float s2 = a0 * a0 + a1 * a1 + a2 * a2 + a3 * a3;
    #pragma unroll
    for (int m = 1; m < 32; m <<= 1) {
        s1 += __shfl_xor(s1, m);
        s2 += __shfl_xor(s2, m);
    }
    const float mu = s1 * (1.f / NF);
    const float var = s2 * (1.f / NF) - mu * mu;
    const float rs = rsqrtf(var + 1e-5f);

    const float4 lw = *(const float4*)(ln_w + l31 * 4);
    const float4 lb = *(const float4*)(ln_b + l31 * 4);
    f32x4 o;
    o.x = (a0 - mu) * rs * lw.x + lb.x;
    o.y = (a1 - mu) * rs * lw.y + lb.y;
    o.z = (a2 - mu) * rs * lw.z + lb.z;
    o.w = (a3 - mu) * rs * lw.w + lb.w;
    if (lane < 32) {
        float* dst = out + ((size_t)b * NNODES + n) * 128 + l31 * 4;
        __builtin_nontemporal_store(o, (f32x4*)dst);
    }
}

// ---------------- launch ----------------

extern "C" void kernel_launch(void* const* d_in, const int* in_sizes, int n_in,
                              void* d_out, int out_size, void* d_ws, size_t ws_size,
                              hipStream_t stream) {
    const float* x    = (const float*)d_in[0];
    const int*   ei   = (const int*)d_in[1];   // int32 [2, E]
    const float* W1   = (const float*)d_in[2];
    const float* b1   = (const float*)d_in[3];
    const float* W2   = (const float*)d_in[4];
    const float* b2   = (const float*)d_in[5];
    const float* ln_w = (const float*)d_in[6];
    const float* ln_b = (const float*)d_in[7];
    float* out = (float*)d_out;

    // workspace layout
    char* ws = (char*)d_ws;
    int*            cnt     = (int*)(ws + 0);          // N ints
    int*            fill    = (int*)(ws + 40192);      // N ints
    int*            row_ptr = (int*)(ws + 80384);      // N+1 ints
    float*          dinv    = (float*)(ws + 120832);   // N floats
    unsigned int*   edge    = (unsigned int*)(ws + 161024);     // E uint (640 KB)
    unsigned short* Wt1     = (unsigned short*)(ws + 801024);   // 32 KB
    unsigned short* Wt2     = (unsigned short*)(ws + 833792);   // 32 KB
    unsigned short* hA16    = (unsigned short*)(ws + 1441024);  // [B,N,128] bf16 (20.48 MB)
    unsigned short* hB16    = (unsigned short*)(ws + 21921024); // [B,N,128] bf16 (20.48 MB)

    // ---- CSR (by dst) + symmetric norm weights + weight transpose ----
    k_init   <<<207, 256, 0, stream>>>(cnt, fill, W1, Wt1, W2, Wt2);
    k_count  <<<(NE + 255) / 256, 256, 0, stream>>>(ei, cnt);
    k_scan   <<<1, 1024, 0, stream>>>(cnt, row_ptr, dinv);
    k_scatter<<<(NE + 255) / 256, 256, 0, stream>>>(ei, row_ptr, fill, dinv, edge);

    // ---- layer 1 matmul: hA16 = bf16(x @ W1), batch-major [B,N,128] ----
    k_mm_mfma<<<(NB * NNODES) / 128, 256, 0, stream>>>(x, Wt1, hA16);

    // ---- fused: hB16 = bf16(relu(agg(hA16)+b1) @ W2) ----
    k_fused<<<8 * ((NNODES + 31) / 32), 512, 0, stream>>>(
        (const unsigned int*)hA16, b1, row_ptr, edge, dinv, Wt2, hB16);

    // ---- layer 2 aggregation + LayerNorm ----
    k_agg_ln<<<(NNODES / 4) * NB, 256, 0, stream>>>((const unsigned int*)hB16, b2,
                                                    row_ptr, edge, dinv,
                                                    ln_w, ln_b, out);
}

// Round 9
// 220.313 us; speedup vs baseline: 1.0453x; 1.0453x over previous
//
#include <hip/hip_runtime.h>
#include <hip/hip_bf16.h>

#define NNODES 10000
#define NB 8
#define NF 128
#define NE 160000

typedef __attribute__((ext_vector_type(8))) short  short8;   // 8 bf16 (A/B frag)
typedef __attribute__((ext_vector_type(8))) unsigned short ushort8;
typedef __attribute__((ext_vector_type(4))) float  f32x4;    // MFMA acc
typedef __attribute__((ext_vector_type(2))) float  f32x2;

// fp32 -> bf16 (RNE) scalar
__device__ __forceinline__ unsigned short f2b(float f) {
    union { float f; unsigned u; } v; v.f = f;
    unsigned r = v.u + 0x7FFF + ((v.u >> 16) & 1);
    return (unsigned short)(r >> 16);
}
// packed pair fp32 -> bf16x2 (v_cvt_pk_bf16_f32)
__device__ __forceinline__ unsigned int f2b2(float a, float b) {
    union { __hip_bfloat162 h; unsigned int u; } v;
    v.h = __float22bfloat162_rn(make_float2(a, b));
    return v.u;
}
__device__ __forceinline__ float b2f_lo(unsigned u) {
    union { unsigned u; float f; } v; v.u = u << 16; return v.f;
}
__device__ __forceinline__ float b2f_hi(unsigned u) {
    union { unsigned u; float f; } v; v.u = u & 0xffff0000u; return v.f;
}

// Swizzled LDS byte offset for a logical [R][128] ushort tile.
__device__ __forceinline__ int swz(int r, int cbyte) {
    return r * 256 + (cbyte ^ ((r & 7) << 4));
}

// ---------------- preprocessing ----------------

__global__ void k_init(int* __restrict__ cnt, int* __restrict__ fill,
                       const float* __restrict__ W1, unsigned short* __restrict__ Wt1,
                       const float* __restrict__ W2, unsigned short* __restrict__ Wt2) {
    const int bid = blockIdx.x;
    const int t = threadIdx.x;
    if (bid < 79) {                       // 79*256 = 20224 >= 2*NNODES
        int i = bid * 256 + t;
        if (i < NNODES) cnt[i] = 0;
        else if (i < 2 * NNODES) fill[i - NNODES] = 0;
    } else {                              // 128 blocks -> 32768 weight elems
        int id = (bid - 79) * 256 + t;
        const float* W = (id < 16384) ? W1 : W2;
        unsigned short* Wt = (id < 16384) ? Wt1 : Wt2;
        int j = id & 16383;
        int n = j >> 7, k = j & 127;
        Wt[(size_t)n * 128 + k] = f2b(W[(size_t)k * 128 + n]);
    }
}

__global__ void k_count(const int* __restrict__ ei, int* __restrict__ cnt) {
    int e = blockIdx.x * blockDim.x + threadIdx.x;
    if (e < NE) atomicAdd(&cnt[ei[NE + e]], 1);
}

// one-block scan of cnt -> row_ptr, plus dinv = rsqrt(deg+1)
__global__ void k_scan(const int* __restrict__ cnt, int* __restrict__ row_ptr,
                       float* __restrict__ dinv) {
    __shared__ int part[1024];
    int t = threadIdx.x;
    const int CH = (NNODES + 1023) / 1024;  // 10
    int lo = t * CH, hi = min(lo + CH, NNODES);
    int s = 0;
    for (int i = lo; i < hi; i++) {
        int c = cnt[i];
        dinv[i] = rsqrtf((float)(c + 1));
        s += c;
    }
    part[t] = s;
    __syncthreads();
    for (int off = 1; off < 1024; off <<= 1) {
        int v = (t >= off) ? part[t - off] : 0;
        __syncthreads();
        part[t] += v;
        __syncthreads();
    }
    int base = part[t] - s;
    for (int i = lo; i < hi; i++) { row_ptr[i] = base; base += cnt[i]; }
    if (t == 1023) row_ptr[NNODES] = part[1023];
}

// ---------------- merged layer-1 matmul + CSR scatter ----------------
// Blocks 0-624: 128-row MFMA tile (measured-best mm config). Blocks 625-1249:
// CSR scatter (NE = 625*256 exactly). Scatter is independent of mm (needs only
// row_ptr/fill/dinv from k_scan) -> hides its ~4 us under mm and removes one
// launch gap. Scatter blocks early-return before any __syncthreads.
__global__ __launch_bounds__(256) void k_mm_sc(const float* __restrict__ Ap,
                                               const unsigned short* __restrict__ Wt,
                                               unsigned short* __restrict__ Cn,
                                               const int* __restrict__ ei,
                                               const int* __restrict__ row_ptr,
                                               int* __restrict__ fill,
                                               const float* __restrict__ dinv,
                                               unsigned int* __restrict__ edge) {
    __shared__ unsigned short wlds[128 * 128];  // 32 KB, XOR-swizzled; reused as C-stage
    const int t = threadIdx.x;

    if (blockIdx.x >= 625) {   // ---- scatter path: edge[pos] = src | bf16(w)<<16
        const int e = (blockIdx.x - 625) * 256 + t;
        const int s = ei[e];
        const int d = ei[NE + e];
        const int pos = row_ptr[d] + atomicAdd(&fill[d], 1);
        edge[pos] = (unsigned)s | ((unsigned)f2b(dinv[s] * dinv[d]) << 16);
        return;
    }

    {   // stage Wt (32 KB), 2 threads/row, 64 ushorts each
        const int r = t >> 1, h = t & 1;
        const ushort8* src = (const ushort8*)(Wt + r * 128 + h * 64);
        #pragma unroll
        for (int i = 0; i < 8; i++)
            *(ushort8*)((char*)wlds + swz(r, h * 128 + i * 16)) = src[i];
    }
    __syncthreads();

    const int wid = t >> 6, lane = t & 63;
    const int quad = lane >> 4, l16 = lane & 15;
    const int m0 = blockIdx.x * 128 + (wid & 1) * 64;  // act row base for this wave
    const int nb = (wid >> 1) * 64;                    // feature base
    const int kq = quad * 8;

    f32x4 acc[4][4] = {};

    #pragma unroll
    for (int ks = 0; ks < 128; ks += 32) {
        short8 bf[4];
        #pragma unroll
        for (int mi = 0; mi < 4; mi++) {
            const float* p = Ap + (size_t)(m0 + mi * 16 + l16) * 128 + ks + kq;
            float4 u0 = *(const float4*)p;
            float4 u1 = *(const float4*)(p + 4);
            union { uint4 u4; short8 s8; } cv;
            cv.u4.x = f2b2(u0.x, u0.y); cv.u4.y = f2b2(u0.z, u0.w);
            cv.u4.z = f2b2(u1.x, u1.y); cv.u4.w = f2b2(u1.z, u1.w);
            bf[mi] = cv.s8;
        }
        short8 af[4];
        #pragma unroll
        for (int ni = 0; ni < 4; ni++) {
            const int row = nb + ni * 16 + l16;
            af[ni] = *(const short8*)((const char*)wlds + swz(row, (ks + kq) * 2));
        }
        #pragma unroll
        for (int mi = 0; mi < 4; mi++)
            #pragma unroll
            for (int ni = 0; ni < 4; ni++)
                acc[mi][ni] = __builtin_amdgcn_mfma_f32_16x16x32_bf16(
                    af[ni], bf[mi], acc[mi][ni], 0, 0, 0);
    }

    // ---- epilogue: stage 128x128 bf16 tile in LDS, coalesced stores ----
    __syncthreads();  // done reading W tile; reuse wlds
    {
        const int rbase = (wid & 1) * 64;
        #pragma unroll
        for (int mi = 0; mi < 4; mi++) {
            int rr = rbase + mi * 16 + l16;
            #pragma unroll
            for (int ni = 0; ni < 4; ni++) {
                uint2 p;
                p.x = f2b2(acc[mi][ni][0], acc[mi][ni][1]);
                p.y = f2b2(acc[mi][ni][2], acc[mi][ni][3]);
                *(uint2*)((char*)wlds + swz(rr, (nb + ni * 16 + quad * 4) * 2)) = p;
            }
        }
    }
    __syncthreads();
    {
        const int r = t >> 1, h = t & 1;     // 128 rows x 2 halves of 128 B
        size_t gm = (size_t)blockIdx.x * 128 + r;   // row index in [B,N] order
        unsigned short* dst = Cn + gm * 128 + h * 64;
        #pragma unroll
        for (int i = 0; i < 8; i++)
            *(ushort8*)(dst + i * 8) =
                *(const ushort8*)((const char*)wlds + swz(r, h * 128 + i * 16));
    }
}

// ---------------- fused layer-1 aggregation + layer-2 matmul ----------------
// EXACT R3 configuration (part of the 222.7 us best total). 32-row tile /
// 512 threads -> 2504 blocks; b = blockIdx&7 binds batch->XCD (R5: losing it
// = 10x FETCH). Tile's CSR edges are contiguous -> cooperatively staged in
// LDS (chunked 2048); row_ptr tile + self/dinv hoisted. Inner loop's only
// global access is the 8-deep U-gather (per-line-bound floor, ~46 us).
__global__ __launch_bounds__(512) void k_fused(const unsigned int* __restrict__ hNu,
                                               const float* __restrict__ bias,
                                               const int* __restrict__ row_ptr,
                                               const unsigned int* __restrict__ edge,
                                               const float* __restrict__ dinv,
                                               const unsigned short* __restrict__ Wt,
                                               unsigned short* __restrict__ Cn) {
    __shared__ unsigned short alds[32 * 128];   // 8 KB act tile; reused as C-stage
    __shared__ unsigned int   elds[2048];       // 8 KB staged edges
    __shared__ int            rplds[33];
    const int t = threadIdx.x;
    const int b = blockIdx.x & 7;
    const int g = blockIdx.x >> 3;
    const int n0 = g * 32;
    const int wid = __builtin_amdgcn_readfirstlane(t >> 6);
    const int lane = t & 63;

    if (t < 33) rplds[t] = row_ptr[min(n0 + t, NNODES)];

    // ---- phase A: aggregate + bias + ReLU, 4 node-rows per wave ----
    const unsigned int* base = hNu + (size_t)b * NNODES * 64 + lane;  // + s*64
    const float bs0 = bias[lane * 2], bs1 = bias[lane * 2 + 1];

    // hoisted self-row + dinv (8 independent loads, one round-trip)
    float a0[4], a1[4];
    #pragma unroll
    for (int i = 0; i < 4; i++) {
        const int n = n0 + wid * 4 + i;
        if (n < NNODES) {
            const float di = dinv[n];
            const float wself = di * di;
            const unsigned int su = base[(size_t)n * 64];
            a0[i] = b2f_lo(su) * wself;
            a1[i] = b2f_hi(su) * wself;
        } else { a0[i] = 0.f; a1[i] = 0.f; }
    }
    __syncthreads();                       // rplds visible
    const int e_lo = rplds[0], e_hi = rplds[32];

    for (int c = e_lo; c < e_hi; c += 2048) {
        const int m = min(2048, e_hi - c);
        if (c != e_lo) __syncthreads();    // prev chunk fully consumed
        for (int k = t; k < m; k += 512) elds[k] = edge[c + k];
        __syncthreads();
        #pragma unroll
        for (int i = 0; i < 4; i++) {
            const int r = wid * 4 + i;
            int e0 = max(rplds[r], c);
            int e1 = min(rplds[r + 1], c + m);
            int e = e0;
            for (; e + 8 <= e1; e += 8) {
                unsigned int E[8];
                #pragma unroll
                for (int j = 0; j < 8; j++) E[j] = elds[e - c + j];
                unsigned int U[8];
                #pragma unroll
                for (int j = 0; j < 8; j++) U[j] = base[(size_t)(E[j] & 0xffffu) * 64];
                #pragma unroll
                for (int j = 0; j < 8; j++) {
                    float w = b2f_hi(E[j]);
                    a0[i] = fmaf(b2f_lo(U[j]), w, a0[i]);
                    a1[i] = fmaf(b2f_hi(U[j]), w, a1[i]);
                }
            }
            for (; e + 4 <= e1; e += 4) {
                unsigned int E[4];
                #pragma unroll
                for (int j = 0; j < 4; j++) E[j] = elds[e - c + j];
                unsigned int U[4];
                #pragma unroll
                for (int j = 0; j < 4; j++) U[j] = base[(size_t)(E[j] & 0xffffu) * 64];
                #pragma unroll
                for (int j = 0; j < 4; j++) {
                    float w = b2f_hi(E[j]);
                    a0[i] = fmaf(b2f_lo(U[j]), w, a0[i]);
                    a1[i] = fmaf(b2f_hi(U[j]), w, a1[i]);
                }
            }
            for (; e < e1; ++e) {
                unsigned int E = elds[e - c];
                float w = b2f_hi(E);
                unsigned int uu = base[(size_t)(E & 0xffffu) * 64];
                a0[i] = fmaf(b2f_lo(uu), w, a0[i]);
                a1[i] = fmaf(b2f_hi(uu), w, a1[i]);
            }
        }
    }

    // bias + ReLU + store to swizzled LDS act tile
    #pragma unroll
    for (int i = 0; i < 4; i++) {
        const int r = wid * 4 + i;
        const float v0 = fmaxf(a0[i] + bs0, 0.f);
        const float v1 = fmaxf(a1[i] + bs1, 0.f);
        *(unsigned int*)((char*)alds + swz(r, lane * 4)) = f2b2(v0, v1);
    }
    __syncthreads();

    // ---- phase B: MFMA, act rows from LDS, W2 frags from global (L2-hot) ----
    const int quad = lane >> 4, l16 = lane & 15;
    const int kq = quad * 8;
    const int rh = (wid & 1) * 16;       // act row half (16 rows)
    const int nb = (wid >> 1) * 32;      // feature quarter (32 feats)

    f32x4 acc[2] = {};
    #pragma unroll
    for (int ks = 0; ks < 128; ks += 32) {
        short8 bf;
        {
            const int row = rh + l16;
            bf = *(const short8*)((const char*)alds + swz(row, (ks + kq) * 2));
        }
        short8 af[2];
        #pragma unroll
        for (int ni = 0; ni < 2; ni++)
            af[ni] = *(const short8*)(Wt + (size_t)(nb + ni * 16 + l16) * 128 + ks + kq);
        #pragma unroll
        for (int ni = 0; ni < 2; ni++)
            acc[ni] = __builtin_amdgcn_mfma_f32_16x16x32_bf16(
                af[ni], bf, acc[ni], 0, 0, 0);
    }

    __syncthreads();  // done reading alds; reuse as C-stage
    {
        const int rr = rh + l16;
        #pragma unroll
        for (int ni = 0; ni < 2; ni++) {
            uint2 p;
            p.x = f2b2(acc[ni][0], acc[ni][1]);
            p.y = f2b2(acc[ni][2], acc[ni][3]);
            *(uint2*)((char*)alds + swz(rr, (nb + ni * 16 + quad * 4) * 2)) = p;
        }
    }
    __syncthreads();
    {
        const int r = t >> 4, h = t & 15;  // 32 rows x 16 chunks of 16 B
        const int n = n0 + r;
        if (n < NNODES) {
            unsigned short* dst = Cn + ((size_t)b * NNODES + n) * 128 + h * 8;
            *(ushort8*)dst = *(const ushort8*)((const char*)alds + swz(r, h * 16));
        }
    }
}

// ---------------- layer-2 aggregation + LayerNorm ----------------
// EXACT R3 configuration (edge-staged; worth ~5 us over the plain loop here).
__global__ __launch_bounds__(256) void k_agg_ln(const unsigned int* __restrict__ hNu,
                                                const float* __restrict__ bias,
                                                const int* __restrict__ row_ptr,
                                                const unsigned int* __restrict__ edge,
                                                const float* __restrict__ dinv,
                                                const float* __restrict__ ln_w,
                                                const float* __restrict__ ln_b,
                                                float* __restrict__ out) {
    __shared__ unsigned int elds[512];
    __shared__ int rplds[5];
    const int t = threadIdx.x;
    const int b = blockIdx.x & 7;
    const int g = blockIdx.x >> 3;
    const int wid = __builtin_amdgcn_readfirstlane(t >> 6);
    const int lane = t & 63;
    const int n = g * 4 + wid;

    if (t < 5) rplds[t] = row_ptr[g * 4 + t];

    const unsigned int* base = hNu + (size_t)b * NNODES * 64 + lane;
    float di = dinv[n];
    float wself = di * di;
    unsigned int u = base[(size_t)n * 64];
    float a0 = b2f_lo(u) * wself;
    float a1 = b2f_hi(u) * wself;

    __syncthreads();
    const int e_lo = rplds[0], e_hi = rplds[4];

    for (int c = e_lo; c < e_hi; c += 512) {
        const int m = min(512, e_hi - c);
        if (c != e_lo) __syncthreads();
        for (int k = t; k < m; k += 256) elds[k] = edge[c + k];
        __syncthreads();
        int e = max(rplds[wid], c);
        const int e1 = min(rplds[wid + 1], c + m);
        for (; e + 8 <= e1; e += 8) {
            unsigned int E[8];
            #pragma unroll
            for (int j = 0; j < 8; j++) E[j] = elds[e - c + j];
            unsigned int U[8];
            #pragma unroll
            for (int j = 0; j < 8; j++) U[j] = base[(size_t)(E[j] & 0xffffu) * 64];
            #pragma unroll
            for (int j = 0; j < 8; j++) {
                float w = b2f_hi(E[j]);
                a0 = fmaf(b2f_lo(U[j]), w, a0);
                a1 = fmaf(b2f_hi(U[j]), w, a1);
            }
        }
        for (; e + 4 <= e1; e += 4) {
            unsigned int E[4];
            #pragma unroll
            for (int j = 0; j < 4; j++) E[j] = elds[e - c + j];
            unsigned int U[4];
            #pragma unroll
            for (int j = 0; j < 4; j++) U[j] = base[(size_t)(E[j] & 0xffffu) * 64];
            #pragma unroll
            for (int j = 0; j < 4; j++) {
                float w = b2f_hi(E[j]);
                a0 = fmaf(b2f_lo(U[j]), w, a0);
                a1 = fmaf(b2f_hi(U[j]), w, a1);
            }
        }
        for (; e < e1; ++e) {
            unsigned int E = elds[e - c];
            float w = b2f_hi(E);
            unsigned int uu = base[(size_t)(E & 0xffffu) * 64];
            a0 = fmaf(b2f_lo(uu), w, a0);
            a1 = fmaf(b2f_hi(uu), w, a1);
        }
    }
    a0 += bias[lane * 2];
    a1 += bias[lane * 2 + 1];

    // LayerNorm over 128 feats spread across the 64-lane wave (2/lane)
    float s1 = a0 + a1;
    float s2 = a0 * a0 + a1 * a1;
    #pragma unroll
    for (int m = 1; m < 64; m <<= 1) {
        s1 += __shfl_xor(s1, m);
        s2 += __shfl_xor(s2, m);
    }
    float mu = s1 * (1.f / NF);
    float var = s2 * (1.f / NF) - mu * mu;
    float rs = rsqrtf(var + 1e-5f);

    float o0 = (a0 - mu) * rs * ln_w[lane * 2] + ln_b[lane * 2];
    float o1 = (a1 - mu) * rs * ln_w[lane * 2 + 1] + ln_b[lane * 2 + 1];
    float* dst = out + ((size_t)b * NNODES + n) * 128 + lane * 2;
    f32x2 o; o.x = o0; o.y = o1;
    __builtin_nontemporal_store(o, (f32x2*)dst);
}

// ---------------- launch ----------------

extern "C" void kernel_launch(void* const* d_in, const int* in_sizes, int n_in,
                              void* d_out, int out_size, void* d_ws, size_t ws_size,
                              hipStream_t stream) {
    const float* x    = (const float*)d_in[0];
    const int*   ei   = (const int*)d_in[1];   // int32 [2, E]
    const float* W1   = (const float*)d_in[2];
    const float* b1   = (const float*)d_in[3];
    const float* W2   = (const float*)d_in[4];
    const float* b2   = (const float*)d_in[5];
    const float* ln_w = (const float*)d_in[6];
    const float* ln_b = (const float*)d_in[7];
    float* out = (float*)d_out;

    // workspace layout
    char* ws = (char*)d_ws;
    int*            cnt     = (int*)(ws + 0);          // N ints
    int*            fill    = (int*)(ws + 40192);      // N ints
    int*            row_ptr = (int*)(ws + 80384);      // N+1 ints
    float*          dinv    = (float*)(ws + 120832);   // N floats
    unsigned int*   edge    = (unsigned int*)(ws + 161024);     // E uint (640 KB)
    unsigned short* Wt1     = (unsigned short*)(ws + 801024);   // 32 KB
    unsigned short* Wt2     = (unsigned short*)(ws + 833792);   // 32 KB
    unsigned short* hA16    = (unsigned short*)(ws + 1441024);  // [B,N,128] bf16 (20.48 MB)
    unsigned short* hB16    = (unsigned short*)(ws + 21921024); // [B,N,128] bf16 (20.48 MB)

    // ---- CSR (by dst) + symmetric norm weights + weight transpose ----
    k_init   <<<207, 256, 0, stream>>>(cnt, fill, W1, Wt1, W2, Wt2);
    k_count  <<<(NE + 255) / 256, 256, 0, stream>>>(ei, cnt);
    k_scan   <<<1, 1024, 0, stream>>>(cnt, row_ptr, dinv);

    // ---- merged: layer-1 matmul (blocks 0-624) + CSR scatter (blocks 625-1249)
    k_mm_sc<<<1250, 256, 0, stream>>>(x, Wt1, hA16, ei, row_ptr, fill, dinv, edge);

    // ---- fused: hB16 = bf16(relu(agg(hA16)+b1) @ W2) ----
    k_fused<<<8 * ((NNODES + 31) / 32), 512, 0, stream>>>(
        (const unsigned int*)hA16, b1, row_ptr, edge, dinv, Wt2, hB16);

    // ---- layer 2 aggregation + LayerNorm ----
    k_agg_ln<<<(NNODES / 4) * NB, 256, 0, stream>>>((const unsigned int*)hB16, b2,
                                                    row_ptr, edge, dinv,
                                                    ln_w, ln_b, out);
}